// Round 7
// baseline (675.611 us; speedup 1.0000x reference)
//
#include <hip/hip_runtime.h>
#include <hip/hip_bf16.h>
#include <math.h>

#define N_TX   100000
#define N_USER 50000
#define F_TX   128
#define F_USER 64
#define HID    64
#define NH     4
#define OUTC   32
#define NE     500000
#define HC1    256          // NH*HID
#define SLOPE  0.2f
#define NB_T   391          // (N_TX+255)/256
#define NB_U   196          // (N_USER+255)/256

__device__ __forceinline__ float elu_f(float x) { return x > 0.f ? x : (expf(x) - 1.f); }
// fast attention-weight exp: softmax normalizes away the ~1ulp v_exp error
__device__ __forceinline__ float lrelu_exp_fast(float x) { x = x > 0.f ? x : SLOPE * x; return __expf(x); }

// ---------------- tiled fp32 GEMM: C = act(A[N,K] @ B[K,M] + bias) ----------------
__global__ __launch_bounds__(256) void gemm_kernel(const float* __restrict__ A,
    const float* __restrict__ B, const float* __restrict__ bias,
    float* __restrict__ C, int N, int K, int M, int act)
{
    __shared__ float As[16][65];
    __shared__ float Bs[16][65];
    const int tid = threadIdx.x;
    const int tx = tid % 16, ty = tid / 16;
    const int row0 = blockIdx.y * 64, col0 = blockIdx.x * 64;
    float acc[4][4] = {};
    for (int k0 = 0; k0 < K; k0 += 16) {
        #pragma unroll
        for (int i = 0; i < 4; ++i) {
            int idx = tid * 4 + i;           // 64x16 A tile
            int r = idx >> 4, kk = idx & 15;
            int gr = row0 + r;
            As[kk][r] = (gr < N) ? A[(size_t)gr * K + (k0 + kk)] : 0.f;
        }
        #pragma unroll
        for (int i = 0; i < 4; ++i) {
            int idx = tid * 4 + i;           // 16x64 B tile
            int kk = idx >> 6, c = idx & 63;
            int gc = col0 + c;
            Bs[kk][c] = (gc < M) ? B[(size_t)(k0 + kk) * M + gc] : 0.f;
        }
        __syncthreads();
        #pragma unroll
        for (int kk = 0; kk < 16; ++kk) {
            float a4[4], b4[4];
            #pragma unroll
            for (int i = 0; i < 4; ++i) a4[i] = As[kk][ty * 4 + i];
            #pragma unroll
            for (int j = 0; j < 4; ++j) b4[j] = Bs[kk][tx * 4 + j];
            #pragma unroll
            for (int i = 0; i < 4; ++i)
                #pragma unroll
                for (int j = 0; j < 4; ++j) acc[i][j] += a4[i] * b4[j];
        }
        __syncthreads();
    }
    #pragma unroll
    for (int i = 0; i < 4; ++i) {
        int r = row0 + ty * 4 + i;
        if (r >= N) continue;
        #pragma unroll
        for (int j = 0; j < 4; ++j) {
            int c = col0 + tx * 4 + j;
            if (c >= M) continue;
            float v = acc[i][j] + (bias ? bias[c] : 0.f);
            if (act == 1) v = elu_f(v);
            C[(size_t)r * M + c] = v;
        }
    }
}

// ====== projection GEMM with fused ELU + dual attention-scalar epilogue (M==64, grid.x==1) ======
__global__ __launch_bounds__(256) void gemm_proj_attn(const float* __restrict__ A,
    const float* __restrict__ B, const float* __restrict__ bias,
    float* __restrict__ C, int N, int K,
    const float* __restrict__ Ma, float* __restrict__ oa,
    const float* __restrict__ Mb, float* __restrict__ ob)
{
    __shared__ float As[16][65];
    __shared__ float Bs[16][65];
    const int tid = threadIdx.x;
    const int tx = tid % 16, ty = tid / 16;
    const int row0 = blockIdx.y * 64;
    float acc[4][4] = {};
    for (int k0 = 0; k0 < K; k0 += 16) {
        #pragma unroll
        for (int i = 0; i < 4; ++i) {
            int idx = tid * 4 + i;           // 64x16 A tile
            int r = idx >> 4, kk = idx & 15;
            int gr = row0 + r;
            As[kk][r] = (gr < N) ? A[(size_t)gr * K + (k0 + kk)] : 0.f;
        }
        #pragma unroll
        for (int i = 0; i < 4; ++i) {
            int idx = tid * 4 + i;           // 16x64 B tile (M==64, no col guard)
            int kk = idx >> 6, c = idx & 63;
            Bs[kk][c] = B[(size_t)(k0 + kk) * 64 + c];
        }
        __syncthreads();
        #pragma unroll
        for (int kk = 0; kk < 16; ++kk) {
            float a4[4], b4[4];
            #pragma unroll
            for (int i = 0; i < 4; ++i) a4[i] = As[kk][ty * 4 + i];
            #pragma unroll
            for (int j = 0; j < 4; ++j) b4[j] = Bs[kk][tx * 4 + j];
            #pragma unroll
            for (int i = 0; i < 4; ++i)
                #pragma unroll
                for (int j = 0; j < 4; ++j) acc[i][j] += a4[i] * b4[j];
        }
        __syncthreads();
    }
    // ---- epilogue: ELU + store row + fused dots against Ma/Mb ([c][4] layout) ----
    const float4 ma0 = *(const float4*)(Ma + (tx * 4 + 0) * 4);
    const float4 ma1 = *(const float4*)(Ma + (tx * 4 + 1) * 4);
    const float4 ma2 = *(const float4*)(Ma + (tx * 4 + 2) * 4);
    const float4 ma3 = *(const float4*)(Ma + (tx * 4 + 3) * 4);
    const float4 mb0 = *(const float4*)(Mb + (tx * 4 + 0) * 4);
    const float4 mb1 = *(const float4*)(Mb + (tx * 4 + 1) * 4);
    const float4 mb2 = *(const float4*)(Mb + (tx * 4 + 2) * 4);
    const float4 mb3 = *(const float4*)(Mb + (tx * 4 + 3) * 4);
    const float4 bb  = *(const float4*)(bias + tx * 4);
    #pragma unroll
    for (int i = 0; i < 4; ++i) {
        int r = row0 + ty * 4 + i;
        bool wr = (r < N);
        float v0 = acc[i][0] + bb.x; v0 = v0 > 0.f ? v0 : (expf(v0) - 1.f);
        float v1 = acc[i][1] + bb.y; v1 = v1 > 0.f ? v1 : (expf(v1) - 1.f);
        float v2 = acc[i][2] + bb.z; v2 = v2 > 0.f ? v2 : (expf(v2) - 1.f);
        float v3 = acc[i][3] + bb.w; v3 = v3 > 0.f ? v3 : (expf(v3) - 1.f);
        if (wr) *(float4*)(C + (size_t)r * 64 + tx * 4) = make_float4(v0, v1, v2, v3);
        float pax = v0 * ma0.x + v1 * ma1.x + v2 * ma2.x + v3 * ma3.x;
        float pay = v0 * ma0.y + v1 * ma1.y + v2 * ma2.y + v3 * ma3.y;
        float paz = v0 * ma0.z + v1 * ma1.z + v2 * ma2.z + v3 * ma3.z;
        float paw = v0 * ma0.w + v1 * ma1.w + v2 * ma2.w + v3 * ma3.w;
        float pbx = v0 * mb0.x + v1 * mb1.x + v2 * mb2.x + v3 * mb3.x;
        float pby = v0 * mb0.y + v1 * mb1.y + v2 * mb2.y + v3 * mb3.y;
        float pbz = v0 * mb0.z + v1 * mb1.z + v2 * mb2.z + v3 * mb3.z;
        float pbw = v0 * mb0.w + v1 * mb1.w + v2 * mb2.w + v3 * mb3.w;
        #pragma unroll
        for (int off = 1; off < 16; off <<= 1) {
            pax += __shfl_xor(pax, off); pay += __shfl_xor(pay, off);
            paz += __shfl_xor(paz, off); paw += __shfl_xor(paw, off);
            pbx += __shfl_xor(pbx, off); pby += __shfl_xor(pby, off);
            pbz += __shfl_xor(pbz, off); pbw += __shfl_xor(pbw, off);
        }
        if (tx == 0 && wr) {
            *(float4*)(oa + (size_t)r * 4) = make_float4(pax, pay, paz, paw);
            *(float4*)(ob + (size_t)r * 4) = make_float4(pbx, pby, pbz, pbw);
        }
    }
}

// ------------- fold attention vectors into weights: Mv[k,h] = sum_c W[k,h*C+c]*a[h,c] -------------
struct AVArgs  { const float* W; const float* a; float* out; int K; int H; int C; };
struct AVArgs6 { AVArgs t[6]; };

__global__ void attn_vecs_kernel(AVArgs6 args)
{
    AVArgs A = args.t[blockIdx.x];
    int tid = threadIdx.x;
    if (tid < A.K * A.H) {
        int k = tid % A.K, h = tid / A.K;
        float s = 0.f;
        const float* wrow = A.W + (size_t)k * (A.H * A.C) + h * A.C;
        const float* arow = A.a + h * A.C;
        for (int c = 0; c < A.C; ++c) s += wrow[c] * arow[c];
        A.out[k * A.H + h] = s;
    }
}

// ================= merged CSR build (both edge types per launch) =================
__global__ __launch_bounds__(256) void hist2_kernel(const int* __restrict__ dst_t,
    const int* __restrict__ dst_u, int* __restrict__ deg_t, int* __restrict__ deg_u)
{
    int e = blockIdx.x * 256 + threadIdx.x;
    if (e < NE) atomicAdd(&deg_t[dst_t[e]], 1);
    else {
        e -= NE;
        if (e < NE) atomicAdd(&deg_u[dst_u[e]], 1);
    }
}

__global__ __launch_bounds__(256) void block_sum2_kernel(const int* __restrict__ deg_t,
    int* __restrict__ bsum_t, const int* __restrict__ deg_u, int* __restrict__ bsum_u)
{
    __shared__ int lds[256];
    int b = blockIdx.x, t = threadIdx.x;
    const int* deg; int* bsum; int Nd, lb;
    if (b < NB_T) { deg = deg_t; bsum = bsum_t; Nd = N_TX; lb = b; }
    else         { deg = deg_u; bsum = bsum_u; Nd = N_USER; lb = b - NB_T; }
    int i = lb * 256 + t;
    lds[t] = (i < Nd) ? deg[i] : 0;
    __syncthreads();
    for (int o = 128; o > 0; o >>= 1) {
        if (t < o) lds[t] += lds[t + o];
        __syncthreads();
    }
    if (t == 0) bsum[lb] = lds[0];
}

__global__ __launch_bounds__(512) void scan_bsum2_kernel(int* __restrict__ bt,
    int* __restrict__ bu)
{
    __shared__ int lds[512];
    int t = threadIdx.x;
    {
        int v = (t < NB_T) ? bt[t] : 0;
        lds[t] = v;
        __syncthreads();
        for (int o = 1; o < 512; o <<= 1) {
            int x = (t >= o) ? lds[t - o] : 0;
            __syncthreads();
            lds[t] += x;
            __syncthreads();
        }
        if (t < NB_T) bt[t] = lds[t] - v;
        __syncthreads();
    }
    {
        int v = (t < NB_U) ? bu[t] : 0;
        lds[t] = v;
        __syncthreads();
        for (int o = 1; o < 512; o <<= 1) {
            int x = (t >= o) ? lds[t - o] : 0;
            __syncthreads();
            lds[t] += x;
            __syncthreads();
        }
        if (t < NB_U) bu[t] = lds[t] - v;
    }
}

__global__ __launch_bounds__(256) void scan_final2_kernel(
    const int* __restrict__ deg_t, const int* __restrict__ be_t,
    int* __restrict__ rowptr_t, int* __restrict__ cur_t,
    const int* __restrict__ deg_u, const int* __restrict__ be_u,
    int* __restrict__ rowptr_u, int* __restrict__ cur_u)
{
    __shared__ int lds[256];
    int b = blockIdx.x, t = threadIdx.x;
    const int* deg; const int* be; int* rowptr; int* cursor; int Nd, lb;
    if (b < NB_T) { deg = deg_t; be = be_t; rowptr = rowptr_t; cursor = cur_t; Nd = N_TX; lb = b; }
    else         { deg = deg_u; be = be_u; rowptr = rowptr_u; cursor = cur_u; Nd = N_USER; lb = b - NB_T; }
    int i = lb * 256 + t;
    int v = (i < Nd) ? deg[i] : 0;
    lds[t] = v;
    __syncthreads();
    for (int o = 1; o < 256; o <<= 1) {
        int x = (t >= o) ? lds[t - o] : 0;
        __syncthreads();
        lds[t] += x;
        __syncthreads();
    }
    int excl = lds[t] - v + be[lb];
    if (i < Nd) {
        rowptr[i] = excl;
        cursor[i] = excl;
        if (i == Nd - 1) rowptr[Nd] = NE;
    }
}

// ---- scatter + edge-weight precompute: one thread per edge, full 64-lane parallelism ----
__global__ __launch_bounds__(256) void scatter2_ew_kernel(
    const int* __restrict__ src_t, const int* __restrict__ dst_t,
    int* __restrict__ cur_t, int* __restrict__ csr_t, float* __restrict__ ew_t,
    const float* __restrict__ als_t, const float* __restrict__ ald_t,
    const int* __restrict__ src_u, const int* __restrict__ dst_u,
    int* __restrict__ cur_u, int* __restrict__ csr_u, float* __restrict__ ew_u,
    const float* __restrict__ als_u, const float* __restrict__ ald_u)
{
    int e = blockIdx.x * 256 + threadIdx.x;
    const int* srcA; const int* dstA; int* cur; int* csr; float* ew;
    const float* als; const float* ald;
    if (e < NE) {
        srcA = src_t; dstA = dst_t; cur = cur_t; csr = csr_t; ew = ew_t;
        als = als_t; ald = ald_t;
    } else {
        e -= NE;
        if (e >= NE) return;
        srcA = src_u; dstA = dst_u; cur = cur_u; csr = csr_u; ew = ew_u;
        als = als_u; ald = ald_u;
    }
    int s = srcA[e], d = dstA[e];
    int p = atomicAdd(&cur[d], 1);
    csr[p] = s;
    float4 a = *(const float4*)(als + (size_t)s * 4);
    float4 b = *(const float4*)(ald + (size_t)d * 4);
    float4 w;
    w.x = lrelu_exp_fast(a.x + b.x);
    w.y = lrelu_exp_fast(a.y + b.y);
    w.z = lrelu_exp_fast(a.z + b.z);
    w.w = lrelu_exp_fast(a.w + b.w);
    *(float4*)(ew + (size_t)p * 4) = w;
}

// ================= conv1 aggregation: one wave per dst node, precomputed weights ==========
__device__ __forceinline__ void acc_edge(int s, int i, int lane,
    const float* __restrict__ ew, const float* __restrict__ hsrc,
    float& a0, float& a1, float& a2, float& a3,
    float& w0, float& w1, float& w2, float& w3)
{
    float4 e = *(const float4*)(ew + (size_t)i * 4);   // streaming broadcast
    float x = hsrc[(size_t)s * 64 + lane];             // 256B gather
    a0 = fmaf(e.x, x, a0); w0 += e.x;
    a1 = fmaf(e.y, x, a1); w1 += e.y;
    a2 = fmaf(e.z, x, a2); w2 += e.z;
    a3 = fmaf(e.w, x, a3); w3 += e.w;
}

__global__ __launch_bounds__(256) void agg_conv1_kernel(const int* __restrict__ rowptr,
    const int* __restrict__ csr, const float* __restrict__ hsrc,
    const float* __restrict__ ew, float* __restrict__ agg, int Nd)
{
    int d = blockIdx.x * 4 + (threadIdx.x >> 6);
    int lane = threadIdx.x & 63;
    if (d >= Nd) return;
    int beg = rowptr[d], end = rowptr[d + 1];
    float a0 = 0.f, a1 = 0.f, a2 = 0.f, a3 = 0.f;
    float w0 = 0.f, w1 = 0.f, w2 = 0.f, w3 = 0.f;
    int i = beg;
    for (; i + 2 <= end; i += 2) {
        int s0 = csr[i], s1 = csr[i + 1];
        acc_edge(s0, i,     lane, ew, hsrc, a0, a1, a2, a3, w0, w1, w2, w3);
        acc_edge(s1, i + 1, lane, ew, hsrc, a0, a1, a2, a3, w0, w1, w2, w3);
    }
    if (i < end)
        acc_edge(csr[i], i, lane, ew, hsrc, a0, a1, a2, a3, w0, w1, w2, w3);
    float* o = agg + (size_t)d * 256;
    o[lane]       = a0 / (w0 + 1e-16f);
    o[64 + lane]  = a1 / (w1 + 1e-16f);
    o[128 + lane] = a2 / (w2 + 1e-16f);
    o[192 + lane] = a3 / (w3 + 1e-16f);
}

// ================= conv1 dst-side transform v7: register-W, broadcast-x matvec ============
// Grid: ceil(Nd/32) blocks x 256 threads = 4 waves; wave w = head w, lane = output col.
// W column W1[k][h*64+lane] lives in 16 NAMED float4 registers (Wr0..Wr15: loaded once,
// coalesced, never addressed -> register-resident; renamed to avoid the W1-param clash).
// x is read as LDS BROADCAST (all lanes same addr -> conflict-free, ~free LDS BW),
// cutting LDS traffic ~64x vs v6 (which was LDS-read-throughput-bound at 1 B/FLOP).
// Node loop `#pragma unroll 1` is load-bearing (r1/r2: cross-iteration ds_read hoisting
// past the VGPR budget -> deterministic scratch spill).
#define TV7_GN 32

#define LDW(q) const float4 Wr##q = make_float4( \
    Wc0[(4*(q)+0)*256], Wc0[(4*(q)+1)*256], Wc0[(4*(q)+2)*256], Wc0[(4*(q)+3)*256]);

#define DOT4(q) { const float4 xv = *(const float4*)(xrow + 4*(q)); \
    acc = fmaf(xv.x, Wr##q.x, acc); acc = fmaf(xv.y, Wr##q.y, acc); \
    acc = fmaf(xv.z, Wr##q.z, acc); acc = fmaf(xv.w, Wr##q.w, acc); }

__global__ __launch_bounds__(256) void transform_v7(
    const float* __restrict__ agg, const float* __restrict__ W1,
    const float* __restrict__ b1, const float* __restrict__ vvec,
    float* __restrict__ dot_part, float* __restrict__ rows_out,
    int Nd, int writeRows)
{
    __shared__ float sX[TV7_GN * 256];        // [node][c], full 4-head rows
    const int tid  = threadIdx.x;
    const int h    = tid >> 6;                // wave = head
    const int lane = tid & 63;                // lane = output col within head
    const int base = blockIdx.x * TV7_GN;

    // ---- W column into 16 named float4 regs (coalesced scalar loads, once/wave) ----
    const float* Wc0 = W1 + h * 64 + lane;
    LDW(0)  LDW(1)  LDW(2)  LDW(3)  LDW(4)  LDW(5)  LDW(6)  LDW(7)
    LDW(8)  LDW(9)  LDW(10) LDW(11) LDW(12) LDW(13) LDW(14) LDW(15)
    const float breg = b1[h * 64 + lane];
    const float vreg = vvec[h * 64 + lane];

    // ---- stage x rows: wave h stages rows h*8..h*8+7, 1 float4/lane = full 1KB row ----
    #pragma unroll
    for (int it = 0; it < TV7_GN / 4; ++it) {
        int r = h * (TV7_GN / 4) + it;
        int g = base + r;
        float4 v = make_float4(0.f, 0.f, 0.f, 0.f);
        if (g < Nd) v = *(const float4*)(agg + (size_t)g * 256 + lane * 4);
        *(float4*)(sX + r * 256 + lane * 4) = v;
    }
    __syncthreads();

    float* dp = dot_part + (size_t)h * Nd;

    #pragma unroll 1
    for (int n = 0; n < TV7_GN; ++n) {
        const float* xrow = sX + n * 256 + h * 64;   // broadcast: same addr all lanes
        float acc = breg;
        DOT4(0)  DOT4(1)  DOT4(2)  DOT4(3)  DOT4(4)  DOT4(5)  DOT4(6)  DOT4(7)
        DOT4(8)  DOT4(9)  DOT4(10) DOT4(11) DOT4(12) DOT4(13) DOT4(14) DOT4(15)
        float v = acc > 0.f ? acc : (expf(acc) - 1.f);
        int g = base + n;
        if (writeRows && g < Nd)
            rows_out[(size_t)g * 256 + h * 64 + lane] = v;   // 256B coalesced/wave
        float s = v * vreg;
        s += __shfl_xor(s, 1);  s += __shfl_xor(s, 2);  s += __shfl_xor(s, 4);
        s += __shfl_xor(s, 8);  s += __shfl_xor(s, 16); s += __shfl_xor(s, 32);
        if (lane == 0 && g < Nd) dp[g] = s;
    }
}

// ------------- sum 4 head partials: o1[i] = sum_h ap[h*N1+i]; o2 likewise -------------
__global__ __launch_bounds__(256) void combine_parts(
    const float* __restrict__ ap, float* __restrict__ o1, int N1,
    const float* __restrict__ bp, float* __restrict__ o2, int N2)
{
    int i = blockIdx.x * 256 + threadIdx.x;
    if (i < N1) {
        o1[i] = ap[i] + ap[N1 + i] + ap[2 * N1 + i] + ap[3 * N1 + i];
    } else {
        int j = i - N1;
        if (j < N2)
            o2[j] = bp[j] + bp[N2 + j] + bp[2 * N2 + j] + bp[3 * N2 + j];
    }
}

// ================= conv2: fused edge-softmax + aggregation + bias/ELU + classifier ==========
__global__ __launch_bounds__(256) void conv2_fused_kernel(const int* __restrict__ rowptr,
    const int* __restrict__ csr, const float* __restrict__ hs2,
    const float* __restrict__ als2, const float* __restrict__ ald2,
    const float* __restrict__ b2, const float* __restrict__ Wc, const float* __restrict__ bc,
    float* __restrict__ out, int Nd)
{
    int d = blockIdx.x * 4 + (threadIdx.x >> 6);
    int lane = threadIdx.x & 63;
    if (d >= Nd) return;
    int beg = rowptr[d], end = rowptr[d + 1];
    float aldd = ald2[d];
    int half = lane >> 5, c = lane & 31;
    float acc = 0.f, wsum = 0.f;
    for (int i = beg + half; i < end; i += 2) {
        int s = csr[i];
        float w = lrelu_exp_fast(als2[s] + aldd);
        acc = fmaf(w, hs2[(size_t)s * 32 + c], acc);
        wsum += w;
    }
    acc  += __shfl_down(acc, 32);
    wsum += __shfl_down(wsum, 32);
    float val = 0.f;
    if (lane < 32) {
        float t2 = acc / (wsum + 1e-16f) + b2[c];
        t2 = t2 > 0.f ? t2 : (expf(t2) - 1.f);
        val = t2 * Wc[c];
    }
    #pragma unroll
    for (int o = 16; o > 0; o >>= 1) val += __shfl_down(val, o);
    if (lane == 0) out[d] = val + bc[0];
}

extern "C" void kernel_launch(void* const* d_in, const int* in_sizes, int n_in,
                              void* d_out, int out_size, void* d_ws, size_t ws_size,
                              hipStream_t stream)
{
    const float* x_tx    = (const float*)d_in[0];
    const float* x_user  = (const float*)d_in[1];
    const int*   ei_u2t  = (const int*)d_in[2];
    const int*   ei_t2u  = (const int*)d_in[3];
    const float* Wp_tx   = (const float*)d_in[4];
    const float* bp_tx   = (const float*)d_in[5];
    const float* Wp_user = (const float*)d_in[6];
    const float* bp_user = (const float*)d_in[7];
    const float* W1_u2t  = (const float*)d_in[8];
    const float* as1_u2t = (const float*)d_in[9];
    const float* ad1_u2t = (const float*)d_in[10];
    const float* b1_u2t  = (const float*)d_in[11];
    const float* W2_u2t  = (const float*)d_in[12];
    const float* as2_u2t = (const float*)d_in[13];
    const float* ad2_u2t = (const float*)d_in[14];
    const float* b2_u2t  = (const float*)d_in[15];
    const float* W1_t2u  = (const float*)d_in[16];
    const float* as1_t2u = (const float*)d_in[17];
    const float* ad1_t2u = (const float*)d_in[18];
    const float* b1_t2u  = (const float*)d_in[19];
    const float* Wc      = (const float*)d_in[24];
    const float* bc      = (const float*)d_in[25];
    float* out = (float*)d_out;
    float* ws  = (float*)d_ws;

    const int* src_u2t = ei_u2t;            // user ids
    const int* dst_u2t = ei_u2t + NE;       // tx ids
    const int* src_t2u = ei_t2u;            // tx ids
    const int* dst_u   = ei_t2u + NE;       // user ids

    // ---- workspace layout (floats) ----
    float* h_tx   = ws;                     //  6,400,000
    float* h_us   = ws + 6400000;           //  3,200,000
    float* hs2    = ws + 9600000;           //  1,600,000  (ald2p/als2p alias here pre-gemm)
    float* als2   = ws + 11200000;          //     50,000
    float* ald2   = ws + 11250000;          //    100,000
    float* als_us = ws + 11350000;          //    200,000  (user src-attn for u2t)
    float* ald_us = ws + 11550000;          //    200,000  (user dst-attn for t2u)
    float* als_tx = ws + 11750000;          //    400,000  (tx src-attn for t2u)
    float* ald_tx = ws + 12150000;          //    400,000  (tx dst-attn for u2t)
    float* agg    = ws + 12550000;          // 25,600,000  (u2t then t2u; u1 in place)
    float* avec   = ws + 38150000;          //      1,536
    float* ald2p = hs2;                     //    400,000  (4 x N_TX, aliases hs2)
    float* als2p = hs2 + 400000;            //    200,000  (4 x N_USER)
    float* ew_t   = ws + 38152000;          //  2,000,000  (4 x NE, csr-order weights u2t)
    float* ew_u   = ws + 40152000;          //  2,000,000  (4 x NE, csr-order weights t2u)
    // ---- int region ----
    int* ibase    = (int*)(ws + 42152000);
    int* deg_t    = ibase;                  //   100,000
    int* deg_u    = ibase + 100000;         //    50,000
    int* rowptr_t = ibase + 150000;         //   100,001
    int* cur_t    = ibase + 250001;         //   100,000
    int* csr_t    = ibase + 350001;         //   500,000
    int* rowptr_u = ibase + 850001;         //    50,001
    int* cur_u    = ibase + 900002;         //    50,000
    int* csr_u    = ibase + 950002;         //   500,000
    int* bsum_t   = ibase + 1450002;        //       512
    int* bsum_u   = ibase + 1450514;        //       512

    float* Msrc_u2t = avec + 0;
    float* Mdst_u2t = avec + 256;
    float* Msrc_t2u = avec + 512;
    float* Mdst_t2u = avec + 768;
    float* vsrc2    = avec + 1024;          // fold(W2, as2): als2 = u1 . vsrc2
    float* vdst2    = avec + 1280;          // fold(W2, ad2): ald2 = t1 . vdst2

    // ---- fold attention vectors into weights ----
    AVArgs6 av;
    av.t[0] = { W1_u2t, as1_u2t, Msrc_u2t, HID, NH, HID };
    av.t[1] = { W1_u2t, ad1_u2t, Mdst_u2t, HID, NH, HID };
    av.t[2] = { W1_t2u, as1_t2u, Msrc_t2u, HID, NH, HID };
    av.t[3] = { W1_t2u, ad1_t2u, Mdst_t2u, HID, NH, HID };
    av.t[4] = { W2_u2t, as2_u2t, vsrc2, HC1, 1, OUTC };
    av.t[5] = { W2_u2t, ad2_u2t, vdst2, HC1, 1, OUTC };
    attn_vecs_kernel<<<6, 256, 0, stream>>>(av);

    // ---- zero degree histograms ----
    hipMemsetAsync(deg_t, 0, 150000 * sizeof(int), stream);

    // ---- CSR histogram + prefix scans (no scatter yet) ----
    hist2_kernel<<<(2 * NE + 255) / 256, 256, 0, stream>>>(dst_u2t, dst_u, deg_t, deg_u);
    block_sum2_kernel<<<NB_T + NB_U, 256, 0, stream>>>(deg_t, bsum_t, deg_u, bsum_u);
    scan_bsum2_kernel<<<1, 512, 0, stream>>>(bsum_t, bsum_u);
    scan_final2_kernel<<<NB_T + NB_U, 256, 0, stream>>>(
        deg_t, bsum_t, rowptr_t, cur_t, deg_u, bsum_u, rowptr_u, cur_u);

    // ---- input projections with fused attention-scalar epilogue ----
    gemm_proj_attn<<<dim3(1, (N_TX + 63) / 64), 256, 0, stream>>>(
        x_tx, Wp_tx, bp_tx, h_tx, N_TX, F_TX,
        Mdst_u2t, ald_tx, Msrc_t2u, als_tx);
    gemm_proj_attn<<<dim3(1, (N_USER + 63) / 64), 256, 0, stream>>>(
        x_user, Wp_user, bp_user, h_us, N_USER, F_USER,
        Msrc_u2t, als_us, Mdst_t2u, ald_us);

    // ---- scatter + edge-weight precompute (both edge types) ----
    scatter2_ew_kernel<<<(2 * NE + 255) / 256, 256, 0, stream>>>(
        src_u2t, dst_u2t, cur_t, csr_t, ew_t, als_us, ald_tx,
        src_t2u, dst_u,   cur_u, csr_u, ew_u, als_tx, ald_us);

    // ================= conv1, u2t (dst = tx): agg -> transform -> ald2 partials ==========
    agg_conv1_kernel<<<(N_TX + 3) / 4, 256, 0, stream>>>(
        rowptr_t, csr_t, h_us, ew_t, agg, N_TX);
    transform_v7<<<(N_TX + TV7_GN - 1) / TV7_GN, 256, 0, stream>>>(
        agg, W1_u2t, b1_u2t, vdst2, ald2p, nullptr, N_TX, 0);

    // ================= conv1, t2u (dst = user): agg -> transform (u1 in place) ==========
    agg_conv1_kernel<<<(N_USER + 3) / 4, 256, 0, stream>>>(
        rowptr_u, csr_u, h_tx, ew_u, agg, N_USER);
    transform_v7<<<(N_USER + TV7_GN - 1) / TV7_GN, 256, 0, stream>>>(
        agg, W1_t2u, b1_t2u, vsrc2, als2p, agg, N_USER, 1);
    float* u1 = agg;

    // ---- combine head partials ----
    combine_parts<<<(N_TX + N_USER + 255) / 256, 256, 0, stream>>>(
        ald2p, ald2, N_TX, als2p, als2, N_USER);

    // ================= conv2 projection + fused conv2/classifier =================
    gemm_kernel<<<dim3(1, (N_USER + 63) / 64), 256, 0, stream>>>(
        u1, W2_u2t, nullptr, hs2, N_USER, HC1, OUTC, 0);
    conv2_fused_kernel<<<(N_TX + 3) / 4, 256, 0, stream>>>(
        rowptr_t, csr_t, hs2, als2, ald2, b2_u2t, Wc, bc, out, N_TX);
}

// Round 9
// 624.231 us; speedup vs baseline: 1.0823x; 1.0823x over previous
//
#include <hip/hip_runtime.h>
#include <hip/hip_bf16.h>
#include <math.h>

#define N_TX   100000
#define N_USER 50000
#define F_TX   128
#define F_USER 64
#define HID    64
#define NH     4
#define OUTC   32
#define NE     500000
#define HC1    256          // NH*HID
#define SLOPE  0.2f
#define NB_T   391          // (N_TX+255)/256
#define NB_U   196          // (N_USER+255)/256

__device__ __forceinline__ float elu_f(float x) { return x > 0.f ? x : (expf(x) - 1.f); }
// fast attention-weight exp: softmax normalizes away the ~1ulp v_exp error
__device__ __forceinline__ float lrelu_exp_fast(float x) { x = x > 0.f ? x : SLOPE * x; return __expf(x); }

// ---------------- tiled fp32 GEMM: C = act(A[N,K] @ B[K,M] + bias) ----------------
__global__ __launch_bounds__(256) void gemm_kernel(const float* __restrict__ A,
    const float* __restrict__ B, const float* __restrict__ bias,
    float* __restrict__ C, int N, int K, int M, int act)
{
    __shared__ float As[16][65];
    __shared__ float Bs[16][65];
    const int tid = threadIdx.x;
    const int tx = tid % 16, ty = tid / 16;
    const int row0 = blockIdx.y * 64, col0 = blockIdx.x * 64;
    float acc[4][4] = {};
    for (int k0 = 0; k0 < K; k0 += 16) {
        #pragma unroll
        for (int i = 0; i < 4; ++i) {
            int idx = tid * 4 + i;           // 64x16 A tile
            int r = idx >> 4, kk = idx & 15;
            int gr = row0 + r;
            As[kk][r] = (gr < N) ? A[(size_t)gr * K + (k0 + kk)] : 0.f;
        }
        #pragma unroll
        for (int i = 0; i < 4; ++i) {
            int idx = tid * 4 + i;           // 16x64 B tile
            int kk = idx >> 6, c = idx & 63;
            int gc = col0 + c;
            Bs[kk][c] = (gc < M) ? B[(size_t)(k0 + kk) * M + gc] : 0.f;
        }
        __syncthreads();
        #pragma unroll
        for (int kk = 0; kk < 16; ++kk) {
            float a4[4], b4[4];
            #pragma unroll
            for (int i = 0; i < 4; ++i) a4[i] = As[kk][ty * 4 + i];
            #pragma unroll
            for (int j = 0; j < 4; ++j) b4[j] = Bs[kk][tx * 4 + j];
            #pragma unroll
            for (int i = 0; i < 4; ++i)
                #pragma unroll
                for (int j = 0; j < 4; ++j) acc[i][j] += a4[i] * b4[j];
        }
        __syncthreads();
    }
    #pragma unroll
    for (int i = 0; i < 4; ++i) {
        int r = row0 + ty * 4 + i;
        if (r >= N) continue;
        #pragma unroll
        for (int j = 0; j < 4; ++j) {
            int c = col0 + tx * 4 + j;
            if (c >= M) continue;
            float v = acc[i][j] + (bias ? bias[c] : 0.f);
            if (act == 1) v = elu_f(v);
            C[(size_t)r * M + c] = v;
        }
    }
}

// ====== projection GEMM with fused ELU + dual attention-scalar epilogue (M==64, grid.x==1) ======
__global__ __launch_bounds__(256) void gemm_proj_attn(const float* __restrict__ A,
    const float* __restrict__ B, const float* __restrict__ bias,
    float* __restrict__ C, int N, int K,
    const float* __restrict__ Ma, float* __restrict__ oa,
    const float* __restrict__ Mb, float* __restrict__ ob)
{
    __shared__ float As[16][65];
    __shared__ float Bs[16][65];
    const int tid = threadIdx.x;
    const int tx = tid % 16, ty = tid / 16;
    const int row0 = blockIdx.y * 64;
    float acc[4][4] = {};
    for (int k0 = 0; k0 < K; k0 += 16) {
        #pragma unroll
        for (int i = 0; i < 4; ++i) {
            int idx = tid * 4 + i;           // 64x16 A tile
            int r = idx >> 4, kk = idx & 15;
            int gr = row0 + r;
            As[kk][r] = (gr < N) ? A[(size_t)gr * K + (k0 + kk)] : 0.f;
        }
        #pragma unroll
        for (int i = 0; i < 4; ++i) {
            int idx = tid * 4 + i;           // 16x64 B tile (M==64, no col guard)
            int kk = idx >> 6, c = idx & 63;
            Bs[kk][c] = B[(size_t)(k0 + kk) * 64 + c];
        }
        __syncthreads();
        #pragma unroll
        for (int kk = 0; kk < 16; ++kk) {
            float a4[4], b4[4];
            #pragma unroll
            for (int i = 0; i < 4; ++i) a4[i] = As[kk][ty * 4 + i];
            #pragma unroll
            for (int j = 0; j < 4; ++j) b4[j] = Bs[kk][tx * 4 + j];
            #pragma unroll
            for (int i = 0; i < 4; ++i)
                #pragma unroll
                for (int j = 0; j < 4; ++j) acc[i][j] += a4[i] * b4[j];
        }
        __syncthreads();
    }
    // ---- epilogue: ELU + store row + fused dots against Ma/Mb ([c][4] layout) ----
    const float4 ma0 = *(const float4*)(Ma + (tx * 4 + 0) * 4);
    const float4 ma1 = *(const float4*)(Ma + (tx * 4 + 1) * 4);
    const float4 ma2 = *(const float4*)(Ma + (tx * 4 + 2) * 4);
    const float4 ma3 = *(const float4*)(Ma + (tx * 4 + 3) * 4);
    const float4 mb0 = *(const float4*)(Mb + (tx * 4 + 0) * 4);
    const float4 mb1 = *(const float4*)(Mb + (tx * 4 + 1) * 4);
    const float4 mb2 = *(const float4*)(Mb + (tx * 4 + 2) * 4);
    const float4 mb3 = *(const float4*)(Mb + (tx * 4 + 3) * 4);
    const float4 bb  = *(const float4*)(bias + tx * 4);
    #pragma unroll
    for (int i = 0; i < 4; ++i) {
        int r = row0 + ty * 4 + i;
        bool wr = (r < N);
        float v0 = acc[i][0] + bb.x; v0 = v0 > 0.f ? v0 : (expf(v0) - 1.f);
        float v1 = acc[i][1] + bb.y; v1 = v1 > 0.f ? v1 : (expf(v1) - 1.f);
        float v2 = acc[i][2] + bb.z; v2 = v2 > 0.f ? v2 : (expf(v2) - 1.f);
        float v3 = acc[i][3] + bb.w; v3 = v3 > 0.f ? v3 : (expf(v3) - 1.f);
        if (wr) *(float4*)(C + (size_t)r * 64 + tx * 4) = make_float4(v0, v1, v2, v3);
        float pax = v0 * ma0.x + v1 * ma1.x + v2 * ma2.x + v3 * ma3.x;
        float pay = v0 * ma0.y + v1 * ma1.y + v2 * ma2.y + v3 * ma3.y;
        float paz = v0 * ma0.z + v1 * ma1.z + v2 * ma2.z + v3 * ma3.z;
        float paw = v0 * ma0.w + v1 * ma1.w + v2 * ma2.w + v3 * ma3.w;
        float pbx = v0 * mb0.x + v1 * mb1.x + v2 * mb2.x + v3 * mb3.x;
        float pby = v0 * mb0.y + v1 * mb1.y + v2 * mb2.y + v3 * mb3.y;
        float pbz = v0 * mb0.z + v1 * mb1.z + v2 * mb2.z + v3 * mb3.z;
        float pbw = v0 * mb0.w + v1 * mb1.w + v2 * mb2.w + v3 * mb3.w;
        #pragma unroll
        for (int off = 1; off < 16; off <<= 1) {
            pax += __shfl_xor(pax, off); pay += __shfl_xor(pay, off);
            paz += __shfl_xor(paz, off); paw += __shfl_xor(paw, off);
            pbx += __shfl_xor(pbx, off); pby += __shfl_xor(pby, off);
            pbz += __shfl_xor(pbz, off); pbw += __shfl_xor(pbw, off);
        }
        if (tx == 0 && wr) {
            *(float4*)(oa + (size_t)r * 4) = make_float4(pax, pay, paz, paw);
            *(float4*)(ob + (size_t)r * 4) = make_float4(pbx, pby, pbz, pbw);
        }
    }
}

// ------------- fold attention vectors into weights: Mv[k,h] = sum_c W[k,h*C+c]*a[h,c] -------------
struct AVArgs  { const float* W; const float* a; float* out; int K; int H; int C; };
struct AVArgs6 { AVArgs t[6]; };

__global__ void attn_vecs_kernel(AVArgs6 args)
{
    AVArgs A = args.t[blockIdx.x];
    int tid = threadIdx.x;
    if (tid < A.K * A.H) {
        int k = tid % A.K, h = tid / A.K;
        float s = 0.f;
        const float* wrow = A.W + (size_t)k * (A.H * A.C) + h * A.C;
        const float* arow = A.a + h * A.C;
        for (int c = 0; c < A.C; ++c) s += wrow[c] * arow[c];
        A.out[k * A.H + h] = s;
    }
}

// ================= merged CSR build (both edge types per launch) =================
__global__ __launch_bounds__(256) void hist2_kernel(const int* __restrict__ dst_t,
    const int* __restrict__ dst_u, int* __restrict__ deg_t, int* __restrict__ deg_u)
{
    int e = blockIdx.x * 256 + threadIdx.x;
    if (e < NE) atomicAdd(&deg_t[dst_t[e]], 1);
    else {
        e -= NE;
        if (e < NE) atomicAdd(&deg_u[dst_u[e]], 1);
    }
}

__global__ __launch_bounds__(256) void block_sum2_kernel(const int* __restrict__ deg_t,
    int* __restrict__ bsum_t, const int* __restrict__ deg_u, int* __restrict__ bsum_u)
{
    __shared__ int lds[256];
    int b = blockIdx.x, t = threadIdx.x;
    const int* deg; int* bsum; int Nd, lb;
    if (b < NB_T) { deg = deg_t; bsum = bsum_t; Nd = N_TX; lb = b; }
    else         { deg = deg_u; bsum = bsum_u; Nd = N_USER; lb = b - NB_T; }
    int i = lb * 256 + t;
    lds[t] = (i < Nd) ? deg[i] : 0;
    __syncthreads();
    for (int o = 128; o > 0; o >>= 1) {
        if (t < o) lds[t] += lds[t + o];
        __syncthreads();
    }
    if (t == 0) bsum[lb] = lds[0];
}

__global__ __launch_bounds__(512) void scan_bsum2_kernel(int* __restrict__ bt,
    int* __restrict__ bu)
{
    __shared__ int lds[512];
    int t = threadIdx.x;
    {
        int v = (t < NB_T) ? bt[t] : 0;
        lds[t] = v;
        __syncthreads();
        for (int o = 1; o < 512; o <<= 1) {
            int x = (t >= o) ? lds[t - o] : 0;
            __syncthreads();
            lds[t] += x;
            __syncthreads();
        }
        if (t < NB_T) bt[t] = lds[t] - v;
        __syncthreads();
    }
    {
        int v = (t < NB_U) ? bu[t] : 0;
        lds[t] = v;
        __syncthreads();
        for (int o = 1; o < 512; o <<= 1) {
            int x = (t >= o) ? lds[t - o] : 0;
            __syncthreads();
            lds[t] += x;
            __syncthreads();
        }
        if (t < NB_U) bu[t] = lds[t] - v;
    }
}

__global__ __launch_bounds__(256) void scan_final2_kernel(
    const int* __restrict__ deg_t, const int* __restrict__ be_t,
    int* __restrict__ rowptr_t, int* __restrict__ cur_t,
    const int* __restrict__ deg_u, const int* __restrict__ be_u,
    int* __restrict__ rowptr_u, int* __restrict__ cur_u)
{
    __shared__ int lds[256];
    int b = blockIdx.x, t = threadIdx.x;
    const int* deg; const int* be; int* rowptr; int* cursor; int Nd, lb;
    if (b < NB_T) { deg = deg_t; be = be_t; rowptr = rowptr_t; cursor = cur_t; Nd = N_TX; lb = b; }
    else         { deg = deg_u; be = be_u; rowptr = rowptr_u; cursor = cur_u; Nd = N_USER; lb = b - NB_T; }
    int i = lb * 256 + t;
    int v = (i < Nd) ? deg[i] : 0;
    lds[t] = v;
    __syncthreads();
    for (int o = 1; o < 256; o <<= 1) {
        int x = (t >= o) ? lds[t - o] : 0;
        __syncthreads();
        lds[t] += x;
        __syncthreads();
    }
    int excl = lds[t] - v + be[lb];
    if (i < Nd) {
        rowptr[i] = excl;
        cursor[i] = excl;
        if (i == Nd - 1) rowptr[Nd] = NE;
    }
}

// ---- scatter + edge-weight precompute: one thread per edge, full 64-lane parallelism ----
__global__ __launch_bounds__(256) void scatter2_ew_kernel(
    const int* __restrict__ src_t, const int* __restrict__ dst_t,
    int* __restrict__ cur_t, int* __restrict__ csr_t, float* __restrict__ ew_t,
    const float* __restrict__ als_t, const float* __restrict__ ald_t,
    const int* __restrict__ src_u, const int* __restrict__ dst_u,
    int* __restrict__ cur_u, int* __restrict__ csr_u, float* __restrict__ ew_u,
    const float* __restrict__ als_u, const float* __restrict__ ald_u)
{
    int e = blockIdx.x * 256 + threadIdx.x;
    const int* srcA; const int* dstA; int* cur; int* csr; float* ew;
    const float* als; const float* ald;
    if (e < NE) {
        srcA = src_t; dstA = dst_t; cur = cur_t; csr = csr_t; ew = ew_t;
        als = als_t; ald = ald_t;
    } else {
        e -= NE;
        if (e >= NE) return;
        srcA = src_u; dstA = dst_u; cur = cur_u; csr = csr_u; ew = ew_u;
        als = als_u; ald = ald_u;
    }
    int s = srcA[e], d = dstA[e];
    int p = atomicAdd(&cur[d], 1);
    csr[p] = s;
    float4 a = *(const float4*)(als + (size_t)s * 4);
    float4 b = *(const float4*)(ald + (size_t)d * 4);
    float4 w;
    w.x = lrelu_exp_fast(a.x + b.x);
    w.y = lrelu_exp_fast(a.y + b.y);
    w.z = lrelu_exp_fast(a.z + b.z);
    w.w = lrelu_exp_fast(a.w + b.w);
    *(float4*)(ew + (size_t)p * 4) = w;
}

// ================= conv1 aggregation: one wave per dst node, precomputed weights ==========
__device__ __forceinline__ void acc_edge(int s, int i, int lane,
    const float* __restrict__ ew, const float* __restrict__ hsrc,
    float& a0, float& a1, float& a2, float& a3,
    float& w0, float& w1, float& w2, float& w3)
{
    float4 e = *(const float4*)(ew + (size_t)i * 4);   // streaming broadcast
    float x = hsrc[(size_t)s * 64 + lane];             // 256B gather
    a0 = fmaf(e.x, x, a0); w0 += e.x;
    a1 = fmaf(e.y, x, a1); w1 += e.y;
    a2 = fmaf(e.z, x, a2); w2 += e.z;
    a3 = fmaf(e.w, x, a3); w3 += e.w;
}

__global__ __launch_bounds__(256) void agg_conv1_kernel(const int* __restrict__ rowptr,
    const int* __restrict__ csr, const float* __restrict__ hsrc,
    const float* __restrict__ ew, float* __restrict__ agg, int Nd)
{
    int d = blockIdx.x * 4 + (threadIdx.x >> 6);
    int lane = threadIdx.x & 63;
    if (d >= Nd) return;
    int beg = rowptr[d], end = rowptr[d + 1];
    float a0 = 0.f, a1 = 0.f, a2 = 0.f, a3 = 0.f;
    float w0 = 0.f, w1 = 0.f, w2 = 0.f, w3 = 0.f;
    int i = beg;
    for (; i + 2 <= end; i += 2) {
        int s0 = csr[i], s1 = csr[i + 1];
        acc_edge(s0, i,     lane, ew, hsrc, a0, a1, a2, a3, w0, w1, w2, w3);
        acc_edge(s1, i + 1, lane, ew, hsrc, a0, a1, a2, a3, w0, w1, w2, w3);
    }
    if (i < end)
        acc_edge(csr[i], i, lane, ew, hsrc, a0, a1, a2, a3, w0, w1, w2, w3);
    float* o = agg + (size_t)d * 256;
    o[lane]       = a0 / (w0 + 1e-16f);
    o[64 + lane]  = a1 / (w1 + 1e-16f);
    o[128 + lane] = a2 / (w2 + 1e-16f);
    o[192 + lane] = a3 / (w3 + 1e-16f);
}

// ================= conv1 dst-side transform v8: v6 pattern, 128-node tile, 8x4/thread ======
// Grid: (ceil(Nd/128), NH). Block: 256 = 16tx x 16ty; thread owns 8 nodes x 4 cols.
// 12 ds_read_b128 per 128 FMAs (0.75x of v6's traffic) and loop overhead amortized over
// 2x the FMAs. Thread's rows are INTERLEAVED (ty + 16*i): a wave's 4 ty-groups read
// ADJACENT rows (bank offset 4 at SXP=68 -> conflict-free); 8-spaced rows would alias to
// identical banks for any float4-aligned stride. `#pragma unroll 1` is load-bearing
// (r1/r2: cross-iteration ds_read hoisting -> deterministic scratch spill).
#define ACC_STEP(i, XS, WV) \
    acc[i][0] = fmaf((XS), (WV).x, acc[i][0]); \
    acc[i][1] = fmaf((XS), (WV).y, acc[i][1]); \
    acc[i][2] = fmaf((XS), (WV).z, acc[i][2]); \
    acc[i][3] = fmaf((XS), (WV).w, acc[i][3]);
#define ACC4(i, XV) \
    ACC_STEP(i, (XV).x, w0) ACC_STEP(i, (XV).y, w1) \
    ACC_STEP(i, (XV).z, w2) ACC_STEP(i, (XV).w, w3)

__global__ __launch_bounds__(256) void transform_v8(
    const float* __restrict__ agg, const float* __restrict__ W1,
    const float* __restrict__ b1, const float* __restrict__ vvec,
    float* __restrict__ dot_part, float* __restrict__ rows_out,
    int Nd, int writeRows)
{
    constexpr int SXP = 68;                   // row stride (floats): adjacent rows 4 banks apart
    __shared__ float sX[128 * SXP];           // [node][c] head slice
    __shared__ float sW[64 * 64];             // [c][col]
    const int tid  = threadIdx.x;
    const int h    = blockIdx.y;
    const int base = blockIdx.x * 128;

    // ---- stage x tile: 8 iters, 16 rows/iter, 256B contiguous per row segment ----
    #pragma unroll
    for (int it = 0; it < 8; ++it) {
        int r  = it * 16 + (tid >> 4);
        int c0 = (tid & 15) * 4;
        int g  = base + r;
        float4 v = make_float4(0.f, 0.f, 0.f, 0.f);
        if (g < Nd) v = *(const float4*)(agg + (size_t)g * 256 + h * 64 + c0);
        *(float4*)(sX + r * SXP + c0) = v;
    }
    // ---- stage W head-slice: row c, cols h*64..h*64+63 ----
    #pragma unroll
    for (int it = 0; it < 4; ++it) {
        int c    = it * 16 + (tid >> 4);
        int col0 = (tid & 15) * 4;
        *(float4*)(sW + c * 64 + col0) =
            *(const float4*)(W1 + (size_t)c * 256 + h * 64 + col0);
    }
    __syncthreads();

    const int tx = tid & 15;                  // col group (4 cols)
    const int ty = tid >> 4;                  // row base; thread rows = ty + 16*i
    float acc[8][4] = {};

    #pragma unroll 1
    for (int c0 = 0; c0 < 64; c0 += 4) {
        const float4 x0 = *(const float4*)(sX + (ty +   0) * SXP + c0);
        const float4 x1 = *(const float4*)(sX + (ty +  16) * SXP + c0);
        const float4 x2 = *(const float4*)(sX + (ty +  32) * SXP + c0);
        const float4 x3 = *(const float4*)(sX + (ty +  48) * SXP + c0);
        const float4 x4 = *(const float4*)(sX + (ty +  64) * SXP + c0);
        const float4 x5 = *(const float4*)(sX + (ty +  80) * SXP + c0);
        const float4 x6 = *(const float4*)(sX + (ty +  96) * SXP + c0);
        const float4 x7 = *(const float4*)(sX + (ty + 112) * SXP + c0);
        const float4 w0 = *(const float4*)(sW + (c0 + 0) * 64 + tx * 4);
        const float4 w1 = *(const float4*)(sW + (c0 + 1) * 64 + tx * 4);
        const float4 w2 = *(const float4*)(sW + (c0 + 2) * 64 + tx * 4);
        const float4 w3 = *(const float4*)(sW + (c0 + 3) * 64 + tx * 4);
        ACC4(0, x0)
        ACC4(1, x1)
        ACC4(2, x2)
        ACC4(3, x3)
        ACC4(4, x4)
        ACC4(5, x5)
        ACC4(6, x6)
        ACC4(7, x7)
    }

    // ---- epilogue: bias + ELU, optional row write, vvec dot-partials ----
    const float4 bb = *(const float4*)(b1   + h * 64 + tx * 4);
    const float4 vv = *(const float4*)(vvec + h * 64 + tx * 4);
    float* dp = dot_part + (size_t)h * Nd;
    #pragma unroll
    for (int i = 0; i < 8; ++i) {
        int g = base + ty + 16 * i;           // uniform across the 16-lane tx group
        if (g >= Nd) continue;
        float v0 = acc[i][0] + bb.x; v0 = v0 > 0.f ? v0 : (expf(v0) - 1.f);
        float v1 = acc[i][1] + bb.y; v1 = v1 > 0.f ? v1 : (expf(v1) - 1.f);
        float v2 = acc[i][2] + bb.z; v2 = v2 > 0.f ? v2 : (expf(v2) - 1.f);
        float v3 = acc[i][3] + bb.w; v3 = v3 > 0.f ? v3 : (expf(v3) - 1.f);
        if (writeRows)
            *(float4*)(rows_out + (size_t)g * 256 + h * 64 + tx * 4) =
                make_float4(v0, v1, v2, v3);
        float s = v0 * vv.x + v1 * vv.y + v2 * vv.z + v3 * vv.w;
        s += __shfl_xor(s, 1); s += __shfl_xor(s, 2);
        s += __shfl_xor(s, 4); s += __shfl_xor(s, 8);
        if (tx == 0) dp[g] = s;
    }
}

// ------------- sum 4 head partials: o1[i] = sum_h ap[h*N1+i]; o2 likewise -------------
__global__ __launch_bounds__(256) void combine_parts(
    const float* __restrict__ ap, float* __restrict__ o1, int N1,
    const float* __restrict__ bp, float* __restrict__ o2, int N2)
{
    int i = blockIdx.x * 256 + threadIdx.x;
    if (i < N1) {
        o1[i] = ap[i] + ap[N1 + i] + ap[2 * N1 + i] + ap[3 * N1 + i];
    } else {
        int j = i - N1;
        if (j < N2)
            o2[j] = bp[j] + bp[N2 + j] + bp[2 * N2 + j] + bp[3 * N2 + j];
    }
}

// ================= conv2: fused edge-softmax + aggregation + bias/ELU + classifier ==========
__global__ __launch_bounds__(256) void conv2_fused_kernel(const int* __restrict__ rowptr,
    const int* __restrict__ csr, const float* __restrict__ hs2,
    const float* __restrict__ als2, const float* __restrict__ ald2,
    const float* __restrict__ b2, const float* __restrict__ Wc, const float* __restrict__ bc,
    float* __restrict__ out, int Nd)
{
    int d = blockIdx.x * 4 + (threadIdx.x >> 6);
    int lane = threadIdx.x & 63;
    if (d >= Nd) return;
    int beg = rowptr[d], end = rowptr[d + 1];
    float aldd = ald2[d];
    int half = lane >> 5, c = lane & 31;
    float acc = 0.f, wsum = 0.f;
    for (int i = beg + half; i < end; i += 2) {
        int s = csr[i];
        float w = lrelu_exp_fast(als2[s] + aldd);
        acc = fmaf(w, hs2[(size_t)s * 32 + c], acc);
        wsum += w;
    }
    acc  += __shfl_down(acc, 32);
    wsum += __shfl_down(wsum, 32);
    float val = 0.f;
    if (lane < 32) {
        float t2 = acc / (wsum + 1e-16f) + b2[c];
        t2 = t2 > 0.f ? t2 : (expf(t2) - 1.f);
        val = t2 * Wc[c];
    }
    #pragma unroll
    for (int o = 16; o > 0; o >>= 1) val += __shfl_down(val, o);
    if (lane == 0) out[d] = val + bc[0];
}

extern "C" void kernel_launch(void* const* d_in, const int* in_sizes, int n_in,
                              void* d_out, int out_size, void* d_ws, size_t ws_size,
                              hipStream_t stream)
{
    const float* x_tx    = (const float*)d_in[0];
    const float* x_user  = (const float*)d_in[1];
    const int*   ei_u2t  = (const int*)d_in[2];
    const int*   ei_t2u  = (const int*)d_in[3];
    const float* Wp_tx   = (const float*)d_in[4];
    const float* bp_tx   = (const float*)d_in[5];
    const float* Wp_user = (const float*)d_in[6];
    const float* bp_user = (const float*)d_in[7];
    const float* W1_u2t  = (const float*)d_in[8];
    const float* as1_u2t = (const float*)d_in[9];
    const float* ad1_u2t = (const float*)d_in[10];
    const float* b1_u2t  = (const float*)d_in[11];
    const float* W2_u2t  = (const float*)d_in[12];
    const float* as2_u2t = (const float*)d_in[13];
    const float* ad2_u2t = (const float*)d_in[14];
    const float* b2_u2t  = (const float*)d_in[15];
    const float* W1_t2u  = (const float*)d_in[16];
    const float* as1_t2u = (const float*)d_in[17];
    const float* ad1_t2u = (const float*)d_in[18];
    const float* b1_t2u  = (const float*)d_in[19];
    const float* Wc      = (const float*)d_in[24];
    const float* bc      = (const float*)d_in[25];
    float* out = (float*)d_out;
    float* ws  = (float*)d_ws;

    const int* src_u2t = ei_u2t;            // user ids
    const int* dst_u2t = ei_u2t + NE;       // tx ids
    const int* src_t2u = ei_t2u;            // tx ids
    const int* dst_u   = ei_t2u + NE;       // user ids

    // ---- workspace layout (floats) ----
    float* h_tx   = ws;                     //  6,400,000
    float* h_us   = ws + 6400000;           //  3,200,000
    float* hs2    = ws + 9600000;           //  1,600,000  (ald2p/als2p alias here pre-gemm)
    float* als2   = ws + 11200000;          //     50,000
    float* ald2   = ws + 11250000;          //    100,000
    float* als_us = ws + 11350000;          //    200,000  (user src-attn for u2t)
    float* ald_us = ws + 11550000;          //    200,000  (user dst-attn for t2u)
    float* als_tx = ws + 11750000;          //    400,000  (tx src-attn for t2u)
    float* ald_tx = ws + 12150000;          //    400,000  (tx dst-attn for u2t)
    float* agg    = ws + 12550000;          // 25,600,000  (u2t then t2u; u1 in place)
    float* avec   = ws + 38150000;          //      1,536
    float* ald2p = hs2;                     //    400,000  (4 x N_TX, aliases hs2)
    float* als2p = hs2 + 400000;            //    200,000  (4 x N_USER)
    float* ew_t   = ws + 38152000;          //  2,000,000  (4 x NE, csr-order weights u2t)
    float* ew_u   = ws + 40152000;          //  2,000,000  (4 x NE, csr-order weights t2u)
    // ---- int region ----
    int* ibase    = (int*)(ws + 42152000);
    int* deg_t    = ibase;                  //   100,000
    int* deg_u    = ibase + 100000;         //    50,000
    int* rowptr_t = ibase + 150000;         //   100,001
    int* cur_t    = ibase + 250001;         //   100,000
    int* csr_t    = ibase + 350001;         //   500,000
    int* rowptr_u = ibase + 850001;         //    50,001
    int* cur_u    = ibase + 900002;         //    50,000
    int* csr_u    = ibase + 950002;         //   500,000
    int* bsum_t   = ibase + 1450002;        //       512
    int* bsum_u   = ibase + 1450514;        //       512

    float* Msrc_u2t = avec + 0;
    float* Mdst_u2t = avec + 256;
    float* Msrc_t2u = avec + 512;
    float* Mdst_t2u = avec + 768;
    float* vsrc2    = avec + 1024;          // fold(W2, as2): als2 = u1 . vsrc2
    float* vdst2    = avec + 1280;          // fold(W2, ad2): ald2 = t1 . vdst2

    // ---- fold attention vectors into weights ----
    AVArgs6 av;
    av.t[0] = { W1_u2t, as1_u2t, Msrc_u2t, HID, NH, HID };
    av.t[1] = { W1_u2t, ad1_u2t, Mdst_u2t, HID, NH, HID };
    av.t[2] = { W1_t2u, as1_t2u, Msrc_t2u, HID, NH, HID };
    av.t[3] = { W1_t2u, ad1_t2u, Mdst_t2u, HID, NH, HID };
    av.t[4] = { W2_u2t, as2_u2t, vsrc2, HC1, 1, OUTC };
    av.t[5] = { W2_u2t, ad2_u2t, vdst2, HC1, 1, OUTC };
    attn_vecs_kernel<<<6, 256, 0, stream>>>(av);

    // ---- zero degree histograms ----
    hipMemsetAsync(deg_t, 0, 150000 * sizeof(int), stream);

    // ---- CSR histogram + prefix scans (no scatter yet) ----
    hist2_kernel<<<(2 * NE + 255) / 256, 256, 0, stream>>>(dst_u2t, dst_u, deg_t, deg_u);
    block_sum2_kernel<<<NB_T + NB_U, 256, 0, stream>>>(deg_t, bsum_t, deg_u, bsum_u);
    scan_bsum2_kernel<<<1, 512, 0, stream>>>(bsum_t, bsum_u);
    scan_final2_kernel<<<NB_T + NB_U, 256, 0, stream>>>(
        deg_t, bsum_t, rowptr_t, cur_t, deg_u, bsum_u, rowptr_u, cur_u);

    // ---- input projections with fused attention-scalar epilogue ----
    gemm_proj_attn<<<dim3(1, (N_TX + 63) / 64), 256, 0, stream>>>(
        x_tx, Wp_tx, bp_tx, h_tx, N_TX, F_TX,
        Mdst_u2t, ald_tx, Msrc_t2u, als_tx);
    gemm_proj_attn<<<dim3(1, (N_USER + 63) / 64), 256, 0, stream>>>(
        x_user, Wp_user, bp_user, h_us, N_USER, F_USER,
        Msrc_u2t, als_us, Mdst_t2u, ald_us);

    // ---- scatter + edge-weight precompute (both edge types) ----
    scatter2_ew_kernel<<<(2 * NE + 255) / 256, 256, 0, stream>>>(
        src_u2t, dst_u2t, cur_t, csr_t, ew_t, als_us, ald_tx,
        src_t2u, dst_u,   cur_u, csr_u, ew_u, als_tx, ald_us);

    // ================= conv1, u2t (dst = tx): agg -> transform -> ald2 partials ==========
    agg_conv1_kernel<<<(N_TX + 3) / 4, 256, 0, stream>>>(
        rowptr_t, csr_t, h_us, ew_t, agg, N_TX);
    transform_v8<<<dim3((N_TX + 127) / 128, NH), 256, 0, stream>>>(
        agg, W1_u2t, b1_u2t, vdst2, ald2p, nullptr, N_TX, 0);

    // ================= conv1, t2u (dst = user): agg -> transform (u1 in place) ==========
    agg_conv1_kernel<<<(N_USER + 3) / 4, 256, 0, stream>>>(
        rowptr_u, csr_u, h_tx, ew_u, agg, N_USER);
    transform_v8<<<dim3((N_USER + 127) / 128, NH), 256, 0, stream>>>(
        agg, W1_t2u, b1_t2u, vsrc2, als2p, agg, N_USER, 1);
    float* u1 = agg;

    // ---- combine head partials ----
    combine_parts<<<(N_TX + N_USER + 255) / 256, 256, 0, stream>>>(
        ald2p, ald2, N_TX, als2p, als2, N_USER);

    // ================= conv2 projection + fused conv2/classifier =================
    gemm_kernel<<<dim3(1, (N_USER + 63) / 64), 256, 0, stream>>>(
        u1, W2_u2t, nullptr, hs2, N_USER, HC1, OUTC, 0);
    conv2_fused_kernel<<<(N_TX + 3) / 4, 256, 0, stream>>>(
        rowptr_t, csr_t, hs2, als2, ald2, b2_u2t, Wc, bc, out, N_TX);
}

// Round 10
// 583.901 us; speedup vs baseline: 1.1571x; 1.0691x over previous
//
#include <hip/hip_runtime.h>
#include <hip/hip_bf16.h>
#include <math.h>

#define N_TX   100000
#define N_USER 50000
#define F_TX   128
#define F_USER 64
#define HID    64
#define NH     4
#define OUTC   32
#define NE     500000
#define HC1    256          // NH*HID
#define SLOPE  0.2f
#define NB_T   391          // (N_TX+255)/256
#define NB_U   196          // (N_USER+255)/256

__device__ __forceinline__ float elu_f(float x) { return x > 0.f ? x : (expf(x) - 1.f); }
// fast attention-weight exp: softmax normalizes away the ~1ulp v_exp error
__device__ __forceinline__ float lrelu_exp_fast(float x) { x = x > 0.f ? x : SLOPE * x; return __expf(x); }

// row-of-acc FMA: acc[i][0..3] += XS * WV.{x,y,z,w}  (named vars only -> register-resident)
#define ACC_STEP(i, XS, WV) \
    acc[i][0] = fmaf((XS), (WV).x, acc[i][0]); \
    acc[i][1] = fmaf((XS), (WV).y, acc[i][1]); \
    acc[i][2] = fmaf((XS), (WV).z, acc[i][2]); \
    acc[i][3] = fmaf((XS), (WV).w, acc[i][3]);
#define ACC4(i, XV) \
    ACC_STEP(i, (XV).x, w0) ACC_STEP(i, (XV).y, w1) \
    ACC_STEP(i, (XV).z, w2) ACC_STEP(i, (XV).w, w3)

// ---------------- tiled fp32 GEMM: C = act(A[N,K] @ B[K,M] + bias) ----------------
// Pad = 68 floats (272B, 16B-aligned) so operand reads are ds_read_b128 (the old 65-pad
// forced scalar ds_read_b32 x8 per kk -> LDS-issue-bound). a-read: 4-addr broadcast,
// rows 4 banks apart (68%32=4) -> conflict-free; b-read: 64 banks/2 = 2-way (free).
__global__ __launch_bounds__(256) void gemm_kernel(const float* __restrict__ A,
    const float* __restrict__ B, const float* __restrict__ bias,
    float* __restrict__ C, int N, int K, int M, int act)
{
    __shared__ float As[16][68];
    __shared__ float Bs[16][68];
    const int tid = threadIdx.x;
    const int tx = tid % 16, ty = tid / 16;
    const int row0 = blockIdx.y * 64, col0 = blockIdx.x * 64;
    float acc[4][4] = {};
    for (int k0 = 0; k0 < K; k0 += 16) {
        #pragma unroll
        for (int i = 0; i < 4; ++i) {
            int idx = tid * 4 + i;           // 64x16 A tile
            int r = idx >> 4, kk = idx & 15;
            int gr = row0 + r;
            As[kk][r] = (gr < N) ? A[(size_t)gr * K + (k0 + kk)] : 0.f;
        }
        #pragma unroll
        for (int i = 0; i < 4; ++i) {
            int idx = tid * 4 + i;           // 16x64 B tile
            int kk = idx >> 6, c = idx & 63;
            int gc = col0 + c;
            Bs[kk][c] = (gc < M) ? B[(size_t)(k0 + kk) * M + gc] : 0.f;
        }
        __syncthreads();
        #pragma unroll 2
        for (int kk = 0; kk < 16; ++kk) {
            const float4 av = *(const float4*)(&As[kk][ty * 4]);
            const float4 bv = *(const float4*)(&Bs[kk][tx * 4]);
            ACC_STEP(0, av.x, bv)
            ACC_STEP(1, av.y, bv)
            ACC_STEP(2, av.z, bv)
            ACC_STEP(3, av.w, bv)
        }
        __syncthreads();
    }
    #pragma unroll
    for (int i = 0; i < 4; ++i) {
        int r = row0 + ty * 4 + i;
        if (r >= N) continue;
        #pragma unroll
        for (int j = 0; j < 4; ++j) {
            int c = col0 + tx * 4 + j;
            if (c >= M) continue;
            float v = acc[i][j] + (bias ? bias[c] : 0.f);
            if (act == 1) v = elu_f(v);
            C[(size_t)r * M + c] = v;
        }
    }
}

// ====== projection GEMM with fused ELU + dual attention-scalar epilogue (M==64, grid.x==1) ======
__global__ __launch_bounds__(256) void gemm_proj_attn(const float* __restrict__ A,
    const float* __restrict__ B, const float* __restrict__ bias,
    float* __restrict__ C, int N, int K,
    const float* __restrict__ Ma, float* __restrict__ oa,
    const float* __restrict__ Mb, float* __restrict__ ob)
{
    __shared__ float As[16][68];
    __shared__ float Bs[16][68];
    const int tid = threadIdx.x;
    const int tx = tid % 16, ty = tid / 16;
    const int row0 = blockIdx.y * 64;
    float acc[4][4] = {};
    for (int k0 = 0; k0 < K; k0 += 16) {
        #pragma unroll
        for (int i = 0; i < 4; ++i) {
            int idx = tid * 4 + i;           // 64x16 A tile
            int r = idx >> 4, kk = idx & 15;
            int gr = row0 + r;
            As[kk][r] = (gr < N) ? A[(size_t)gr * K + (k0 + kk)] : 0.f;
        }
        #pragma unroll
        for (int i = 0; i < 4; ++i) {
            int idx = tid * 4 + i;           // 16x64 B tile (M==64, no col guard)
            int kk = idx >> 6, c = idx & 63;
            Bs[kk][c] = B[(size_t)(k0 + kk) * 64 + c];
        }
        __syncthreads();
        #pragma unroll 2
        for (int kk = 0; kk < 16; ++kk) {
            const float4 av = *(const float4*)(&As[kk][ty * 4]);
            const float4 bv = *(const float4*)(&Bs[kk][tx * 4]);
            ACC_STEP(0, av.x, bv)
            ACC_STEP(1, av.y, bv)
            ACC_STEP(2, av.z, bv)
            ACC_STEP(3, av.w, bv)
        }
        __syncthreads();
    }
    // ---- epilogue: ELU + store row + fused dots against Ma/Mb ([c][4] layout) ----
    const float4 ma0 = *(const float4*)(Ma + (tx * 4 + 0) * 4);
    const float4 ma1 = *(const float4*)(Ma + (tx * 4 + 1) * 4);
    const float4 ma2 = *(const float4*)(Ma + (tx * 4 + 2) * 4);
    const float4 ma3 = *(const float4*)(Ma + (tx * 4 + 3) * 4);
    const float4 mb0 = *(const float4*)(Mb + (tx * 4 + 0) * 4);
    const float4 mb1 = *(const float4*)(Mb + (tx * 4 + 1) * 4);
    const float4 mb2 = *(const float4*)(Mb + (tx * 4 + 2) * 4);
    const float4 mb3 = *(const float4*)(Mb + (tx * 4 + 3) * 4);
    const float4 bb  = *(const float4*)(bias + tx * 4);
    #pragma unroll
    for (int i = 0; i < 4; ++i) {
        int r = row0 + ty * 4 + i;
        bool wr = (r < N);
        float v0 = acc[i][0] + bb.x; v0 = v0 > 0.f ? v0 : (expf(v0) - 1.f);
        float v1 = acc[i][1] + bb.y; v1 = v1 > 0.f ? v1 : (expf(v1) - 1.f);
        float v2 = acc[i][2] + bb.z; v2 = v2 > 0.f ? v2 : (expf(v2) - 1.f);
        float v3 = acc[i][3] + bb.w; v3 = v3 > 0.f ? v3 : (expf(v3) - 1.f);
        if (wr) *(float4*)(C + (size_t)r * 64 + tx * 4) = make_float4(v0, v1, v2, v3);
        float pax = v0 * ma0.x + v1 * ma1.x + v2 * ma2.x + v3 * ma3.x;
        float pay = v0 * ma0.y + v1 * ma1.y + v2 * ma2.y + v3 * ma3.y;
        float paz = v0 * ma0.z + v1 * ma1.z + v2 * ma2.z + v3 * ma3.z;
        float paw = v0 * ma0.w + v1 * ma1.w + v2 * ma2.w + v3 * ma3.w;
        float pbx = v0 * mb0.x + v1 * mb1.x + v2 * mb2.x + v3 * mb3.x;
        float pby = v0 * mb0.y + v1 * mb1.y + v2 * mb2.y + v3 * mb3.y;
        float pbz = v0 * mb0.z + v1 * mb1.z + v2 * mb2.z + v3 * mb3.z;
        float pbw = v0 * mb0.w + v1 * mb1.w + v2 * mb2.w + v3 * mb3.w;
        #pragma unroll
        for (int off = 1; off < 16; off <<= 1) {
            pax += __shfl_xor(pax, off); pay += __shfl_xor(pay, off);
            paz += __shfl_xor(paz, off); paw += __shfl_xor(paw, off);
            pbx += __shfl_xor(pbx, off); pby += __shfl_xor(pby, off);
            pbz += __shfl_xor(pbz, off); pbw += __shfl_xor(pbw, off);
        }
        if (tx == 0 && wr) {
            *(float4*)(oa + (size_t)r * 4) = make_float4(pax, pay, paz, paw);
            *(float4*)(ob + (size_t)r * 4) = make_float4(pbx, pby, pbz, pbw);
        }
    }
}

// ------------- fold attention vectors into weights: Mv[k,h] = sum_c W[k,h*C+c]*a[h,c] -------------
struct AVArgs  { const float* W; const float* a; float* out; int K; int H; int C; };
struct AVArgs6 { AVArgs t[6]; };

__global__ void attn_vecs_kernel(AVArgs6 args)
{
    AVArgs A = args.t[blockIdx.x];
    int tid = threadIdx.x;
    if (tid < A.K * A.H) {
        int k = tid % A.K, h = tid / A.K;
        float s = 0.f;
        const float* wrow = A.W + (size_t)k * (A.H * A.C) + h * A.C;
        const float* arow = A.a + h * A.C;
        for (int c = 0; c < A.C; ++c) s += wrow[c] * arow[c];
        A.out[k * A.H + h] = s;
    }
}

// ================= merged CSR build (both edge types per launch) =================
__global__ __launch_bounds__(256) void hist2_kernel(const int* __restrict__ dst_t,
    const int* __restrict__ dst_u, int* __restrict__ deg_t, int* __restrict__ deg_u)
{
    int e = blockIdx.x * 256 + threadIdx.x;
    if (e < NE) atomicAdd(&deg_t[dst_t[e]], 1);
    else {
        e -= NE;
        if (e < NE) atomicAdd(&deg_u[dst_u[e]], 1);
    }
}

__global__ __launch_bounds__(256) void block_sum2_kernel(const int* __restrict__ deg_t,
    int* __restrict__ bsum_t, const int* __restrict__ deg_u, int* __restrict__ bsum_u)
{
    __shared__ int lds[256];
    int b = blockIdx.x, t = threadIdx.x;
    const int* deg; int* bsum; int Nd, lb;
    if (b < NB_T) { deg = deg_t; bsum = bsum_t; Nd = N_TX; lb = b; }
    else         { deg = deg_u; bsum = bsum_u; Nd = N_USER; lb = b - NB_T; }
    int i = lb * 256 + t;
    lds[t] = (i < Nd) ? deg[i] : 0;
    __syncthreads();
    for (int o = 128; o > 0; o >>= 1) {
        if (t < o) lds[t] += lds[t + o];
        __syncthreads();
    }
    if (t == 0) bsum[lb] = lds[0];
}

__global__ __launch_bounds__(512) void scan_bsum2_kernel(int* __restrict__ bt,
    int* __restrict__ bu)
{
    __shared__ int lds[512];
    int t = threadIdx.x;
    {
        int v = (t < NB_T) ? bt[t] : 0;
        lds[t] = v;
        __syncthreads();
        for (int o = 1; o < 512; o <<= 1) {
            int x = (t >= o) ? lds[t - o] : 0;
            __syncthreads();
            lds[t] += x;
            __syncthreads();
        }
        if (t < NB_T) bt[t] = lds[t] - v;
        __syncthreads();
    }
    {
        int v = (t < NB_U) ? bu[t] : 0;
        lds[t] = v;
        __syncthreads();
        for (int o = 1; o < 512; o <<= 1) {
            int x = (t >= o) ? lds[t - o] : 0;
            __syncthreads();
            lds[t] += x;
            __syncthreads();
        }
        if (t < NB_U) bu[t] = lds[t] - v;
    }
}

__global__ __launch_bounds__(256) void scan_final2_kernel(
    const int* __restrict__ deg_t, const int* __restrict__ be_t,
    int* __restrict__ rowptr_t, int* __restrict__ cur_t,
    const int* __restrict__ deg_u, const int* __restrict__ be_u,
    int* __restrict__ rowptr_u, int* __restrict__ cur_u)
{
    __shared__ int lds[256];
    int b = blockIdx.x, t = threadIdx.x;
    const int* deg; const int* be; int* rowptr; int* cursor; int Nd, lb;
    if (b < NB_T) { deg = deg_t; be = be_t; rowptr = rowptr_t; cursor = cur_t; Nd = N_TX; lb = b; }
    else         { deg = deg_u; be = be_u; rowptr = rowptr_u; cursor = cur_u; Nd = N_USER; lb = b - NB_T; }
    int i = lb * 256 + t;
    int v = (i < Nd) ? deg[i] : 0;
    lds[t] = v;
    __syncthreads();
    for (int o = 1; o < 256; o <<= 1) {
        int x = (t >= o) ? lds[t - o] : 0;
        __syncthreads();
        lds[t] += x;
        __syncthreads();
    }
    int excl = lds[t] - v + be[lb];
    if (i < Nd) {
        rowptr[i] = excl;
        cursor[i] = excl;
        if (i == Nd - 1) rowptr[Nd] = NE;
    }
}

// ---- scatter + edge-weight precompute: one thread per edge, full 64-lane parallelism ----
__global__ __launch_bounds__(256) void scatter2_ew_kernel(
    const int* __restrict__ src_t, const int* __restrict__ dst_t,
    int* __restrict__ cur_t, int* __restrict__ csr_t, float* __restrict__ ew_t,
    const float* __restrict__ als_t, const float* __restrict__ ald_t,
    const int* __restrict__ src_u, const int* __restrict__ dst_u,
    int* __restrict__ cur_u, int* __restrict__ csr_u, float* __restrict__ ew_u,
    const float* __restrict__ als_u, const float* __restrict__ ald_u)
{
    int e = blockIdx.x * 256 + threadIdx.x;
    const int* srcA; const int* dstA; int* cur; int* csr; float* ew;
    const float* als; const float* ald;
    if (e < NE) {
        srcA = src_t; dstA = dst_t; cur = cur_t; csr = csr_t; ew = ew_t;
        als = als_t; ald = ald_t;
    } else {
        e -= NE;
        if (e >= NE) return;
        srcA = src_u; dstA = dst_u; cur = cur_u; csr = csr_u; ew = ew_u;
        als = als_u; ald = ald_u;
    }
    int s = srcA[e], d = dstA[e];
    int p = atomicAdd(&cur[d], 1);
    csr[p] = s;
    float4 a = *(const float4*)(als + (size_t)s * 4);
    float4 b = *(const float4*)(ald + (size_t)d * 4);
    float4 w;
    w.x = lrelu_exp_fast(a.x + b.x);
    w.y = lrelu_exp_fast(a.y + b.y);
    w.z = lrelu_exp_fast(a.z + b.z);
    w.w = lrelu_exp_fast(a.w + b.w);
    *(float4*)(ew + (size_t)p * 4) = w;
}

// ================= conv1 aggregation: one wave per dst node, precomputed weights ==========
__device__ __forceinline__ void acc_edge(int s, int i, int lane,
    const float* __restrict__ ew, const float* __restrict__ hsrc,
    float& a0, float& a1, float& a2, float& a3,
    float& w0, float& w1, float& w2, float& w3)
{
    float4 e = *(const float4*)(ew + (size_t)i * 4);   // streaming broadcast
    float x = hsrc[(size_t)s * 64 + lane];             // 256B gather
    a0 = fmaf(e.x, x, a0); w0 += e.x;
    a1 = fmaf(e.y, x, a1); w1 += e.y;
    a2 = fmaf(e.z, x, a2); w2 += e.z;
    a3 = fmaf(e.w, x, a3); w3 += e.w;
}

__global__ __launch_bounds__(256) void agg_conv1_kernel(const int* __restrict__ rowptr,
    const int* __restrict__ csr, const float* __restrict__ hsrc,
    const float* __restrict__ ew, float* __restrict__ agg, int Nd)
{
    int d = blockIdx.x * 4 + (threadIdx.x >> 6);
    int lane = threadIdx.x & 63;
    if (d >= Nd) return;
    int beg = rowptr[d], end = rowptr[d + 1];
    float a0 = 0.f, a1 = 0.f, a2 = 0.f, a3 = 0.f;
    float w0 = 0.f, w1 = 0.f, w2 = 0.f, w3 = 0.f;
    int i = beg;
    for (; i + 2 <= end; i += 2) {
        int s0 = csr[i], s1 = csr[i + 1];
        acc_edge(s0, i,     lane, ew, hsrc, a0, a1, a2, a3, w0, w1, w2, w3);
        acc_edge(s1, i + 1, lane, ew, hsrc, a0, a1, a2, a3, w0, w1, w2, w3);
    }
    if (i < end)
        acc_edge(csr[i], i, lane, ew, hsrc, a0, a1, a2, a3, w0, w1, w2, w3);
    float* o = agg + (size_t)d * 256;
    o[lane]       = a0 / (w0 + 1e-16f);
    o[64 + lane]  = a1 / (w1 + 1e-16f);
    o[128 + lane] = a2 / (w2 + 1e-16f);
    o[192 + lane] = a3 / (w3 + 1e-16f);
}

// ================= conv1 dst-side transform v6 (proven 67us): 64-node tile, 4x4/thread ====
// `#pragma unroll 1` on the k-loop is load-bearing: full unroll let the scheduler hoist
// ds_reads past the VGPR budget -> deterministic 2.5 GB/launch scratch spill (r1/r2).
// v8 (128-tile) traded LDS traffic for occupancy (51KB -> 3 blk/CU) and lost; v6 stands.
__global__ __launch_bounds__(256) void transform_v6(
    const float* __restrict__ agg, const float* __restrict__ W1,
    const float* __restrict__ b1, const float* __restrict__ vvec,
    float* __restrict__ dot_part, float* __restrict__ rows_out,
    int Nd, int writeRows)
{
    constexpr int SXP = 68;                   // row stride (floats): 272B, 16B-aligned
    __shared__ float sX[64 * SXP];            // [node][c]
    __shared__ float sW[64 * 64];             // [c][col]
    const int tid  = threadIdx.x;
    const int w    = tid >> 6;
    const int lane = tid & 63;
    const int h    = blockIdx.y;
    const int base = blockIdx.x * 64;

    // ---- stage x tile: wave w stages node rows, 256B contiguous per row ----
    #pragma unroll
    for (int it = 0; it < 4; ++it) {
        int r  = w * 16 + it * 4 + (lane >> 4);
        int c0 = (lane & 15) * 4;
        int g  = base + r;
        float4 v = make_float4(0.f, 0.f, 0.f, 0.f);
        if (g < Nd) v = *(const float4*)(agg + (size_t)g * 256 + h * 64 + c0);
        *(float4*)(sX + r * SXP + c0) = v;
    }
    // ---- stage W head-slice: row c, cols h*64..h*64+63 ----
    #pragma unroll
    for (int it = 0; it < 4; ++it) {
        int c    = w * 16 + it * 4 + (lane >> 4);
        int col0 = (lane & 15) * 4;
        *(float4*)(sW + c * 64 + col0) =
            *(const float4*)(W1 + (size_t)c * 256 + h * 64 + col0);
    }
    __syncthreads();

    const int tx = tid & 15;                  // col group (4 cols)
    const int ty = tid >> 4;                  // node group (4 nodes)
    float acc[4][4] = {};

    #pragma unroll 1
    for (int c0 = 0; c0 < 64; c0 += 4) {
        const float4 x0 = *(const float4*)(sX + (ty * 4 + 0) * SXP + c0);
        const float4 x1 = *(const float4*)(sX + (ty * 4 + 1) * SXP + c0);
        const float4 x2 = *(const float4*)(sX + (ty * 4 + 2) * SXP + c0);
        const float4 x3 = *(const float4*)(sX + (ty * 4 + 3) * SXP + c0);
        const float4 w0 = *(const float4*)(sW + (c0 + 0) * 64 + tx * 4);
        const float4 w1 = *(const float4*)(sW + (c0 + 1) * 64 + tx * 4);
        const float4 w2 = *(const float4*)(sW + (c0 + 2) * 64 + tx * 4);
        const float4 w3 = *(const float4*)(sW + (c0 + 3) * 64 + tx * 4);
        ACC4(0, x0)
        ACC4(1, x1)
        ACC4(2, x2)
        ACC4(3, x3)
    }

    // ---- epilogue: bias + ELU, optional row write, vvec dot-partials ----
    const float4 bb = *(const float4*)(b1   + h * 64 + tx * 4);
    const float4 vv = *(const float4*)(vvec + h * 64 + tx * 4);
    float* dp = dot_part + (size_t)h * Nd;
    #pragma unroll
    for (int i = 0; i < 4; ++i) {
        int g = base + ty * 4 + i;            // uniform across the 16-lane tx group
        if (g >= Nd) continue;
        float v0 = acc[i][0] + bb.x; v0 = v0 > 0.f ? v0 : (expf(v0) - 1.f);
        float v1 = acc[i][1] + bb.y; v1 = v1 > 0.f ? v1 : (expf(v1) - 1.f);
        float v2 = acc[i][2] + bb.z; v2 = v2 > 0.f ? v2 : (expf(v2) - 1.f);
        float v3 = acc[i][3] + bb.w; v3 = v3 > 0.f ? v3 : (expf(v3) - 1.f);
        if (writeRows)
            *(float4*)(rows_out + (size_t)g * 256 + h * 64 + tx * 4) =
                make_float4(v0, v1, v2, v3);
        float s = v0 * vv.x + v1 * vv.y + v2 * vv.z + v3 * vv.w;
        s += __shfl_xor(s, 1); s += __shfl_xor(s, 2);
        s += __shfl_xor(s, 4); s += __shfl_xor(s, 8);
        if (tx == 0) dp[g] = s;
    }
}

// ------------- sum 4 head partials: o1[i] = sum_h ap[h*N1+i]; o2 likewise -------------
__global__ __launch_bounds__(256) void combine_parts(
    const float* __restrict__ ap, float* __restrict__ o1, int N1,
    const float* __restrict__ bp, float* __restrict__ o2, int N2)
{
    int i = blockIdx.x * 256 + threadIdx.x;
    if (i < N1) {
        o1[i] = ap[i] + ap[N1 + i] + ap[2 * N1 + i] + ap[3 * N1 + i];
    } else {
        int j = i - N1;
        if (j < N2)
            o2[j] = bp[j] + bp[N2 + j] + bp[2 * N2 + j] + bp[3 * N2 + j];
    }
}

// ================= conv2: fused edge-softmax + aggregation + bias/ELU + classifier ==========
__global__ __launch_bounds__(256) void conv2_fused_kernel(const int* __restrict__ rowptr,
    const int* __restrict__ csr, const float* __restrict__ hs2,
    const float* __restrict__ als2, const float* __restrict__ ald2,
    const float* __restrict__ b2, const float* __restrict__ Wc, const float* __restrict__ bc,
    float* __restrict__ out, int Nd)
{
    int d = blockIdx.x * 4 + (threadIdx.x >> 6);
    int lane = threadIdx.x & 63;
    if (d >= Nd) return;
    int beg = rowptr[d], end = rowptr[d + 1];
    float aldd = ald2[d];
    int half = lane >> 5, c = lane & 31;
    float acc = 0.f, wsum = 0.f;
    for (int i = beg + half; i < end; i += 2) {
        int s = csr[i];
        float w = lrelu_exp_fast(als2[s] + aldd);
        acc = fmaf(w, hs2[(size_t)s * 32 + c], acc);
        wsum += w;
    }
    acc  += __shfl_down(acc, 32);
    wsum += __shfl_down(wsum, 32);
    float val = 0.f;
    if (lane < 32) {
        float t2 = acc / (wsum + 1e-16f) + b2[c];
        t2 = t2 > 0.f ? t2 : (expf(t2) - 1.f);
        val = t2 * Wc[c];
    }
    #pragma unroll
    for (int o = 16; o > 0; o >>= 1) val += __shfl_down(val, o);
    if (lane == 0) out[d] = val + bc[0];
}

extern "C" void kernel_launch(void* const* d_in, const int* in_sizes, int n_in,
                              void* d_out, int out_size, void* d_ws, size_t ws_size,
                              hipStream_t stream)
{
    const float* x_tx    = (const float*)d_in[0];
    const float* x_user  = (const float*)d_in[1];
    const int*   ei_u2t  = (const int*)d_in[2];
    const int*   ei_t2u  = (const int*)d_in[3];
    const float* Wp_tx   = (const float*)d_in[4];
    const float* bp_tx   = (const float*)d_in[5];
    const float* Wp_user = (const float*)d_in[6];
    const float* bp_user = (const float*)d_in[7];
    const float* W1_u2t  = (const float*)d_in[8];
    const float* as1_u2t = (const float*)d_in[9];
    const float* ad1_u2t = (const float*)d_in[10];
    const float* b1_u2t  = (const float*)d_in[11];
    const float* W2_u2t  = (const float*)d_in[12];
    const float* as2_u2t = (const float*)d_in[13];
    const float* ad2_u2t = (const float*)d_in[14];
    const float* b2_u2t  = (const float*)d_in[15];
    const float* W1_t2u  = (const float*)d_in[16];
    const float* as1_t2u = (const float*)d_in[17];
    const float* ad1_t2u = (const float*)d_in[18];
    const float* b1_t2u  = (const float*)d_in[19];
    const float* Wc      = (const float*)d_in[24];
    const float* bc      = (const float*)d_in[25];
    float* out = (float*)d_out;
    float* ws  = (float*)d_ws;

    const int* src_u2t = ei_u2t;            // user ids
    const int* dst_u2t = ei_u2t + NE;       // tx ids
    const int* src_t2u = ei_t2u;            // tx ids
    const int* dst_u   = ei_t2u + NE;       // user ids

    // ---- workspace layout (floats) ----
    float* h_tx   = ws;                     //  6,400,000
    float* h_us   = ws + 6400000;           //  3,200,000
    float* hs2    = ws + 9600000;           //  1,600,000  (ald2p/als2p alias here pre-gemm)
    float* als2   = ws + 11200000;          //     50,000
    float* ald2   = ws + 11250000;          //    100,000
    float* als_us = ws + 11350000;          //    200,000  (user src-attn for u2t)
    float* ald_us = ws + 11550000;          //    200,000  (user dst-attn for t2u)
    float* als_tx = ws + 11750000;          //    400,000  (tx src-attn for t2u)
    float* ald_tx = ws + 12150000;          //    400,000  (tx dst-attn for u2t)
    float* agg    = ws + 12550000;          // 25,600,000  (u2t then t2u; u1 in place)
    float* avec   = ws + 38150000;          //      1,536
    float* ald2p = hs2;                     //    400,000  (4 x N_TX, aliases hs2)
    float* als2p = hs2 + 400000;            //    200,000  (4 x N_USER)
    float* ew_t   = ws + 38152000;          //  2,000,000  (4 x NE, csr-order weights u2t)
    float* ew_u   = ws + 40152000;          //  2,000,000  (4 x NE, csr-order weights t2u)
    // ---- int region ----
    int* ibase    = (int*)(ws + 42152000);
    int* deg_t    = ibase;                  //   100,000
    int* deg_u    = ibase + 100000;         //    50,000
    int* rowptr_t = ibase + 150000;         //   100,001
    int* cur_t    = ibase + 250001;         //   100,000
    int* csr_t    = ibase + 350001;         //   500,000
    int* rowptr_u = ibase + 850001;         //    50,001
    int* cur_u    = ibase + 900002;         //    50,000
    int* csr_u    = ibase + 950002;         //   500,000
    int* bsum_t   = ibase + 1450002;        //       512
    int* bsum_u   = ibase + 1450514;        //       512

    float* Msrc_u2t = avec + 0;
    float* Mdst_u2t = avec + 256;
    float* Msrc_t2u = avec + 512;
    float* Mdst_t2u = avec + 768;
    float* vsrc2    = avec + 1024;          // fold(W2, as2): als2 = u1 . vsrc2
    float* vdst2    = avec + 1280;          // fold(W2, ad2): ald2 = t1 . vdst2

    // ---- fold attention vectors into weights ----
    AVArgs6 av;
    av.t[0] = { W1_u2t, as1_u2t, Msrc_u2t, HID, NH, HID };
    av.t[1] = { W1_u2t, ad1_u2t, Mdst_u2t, HID, NH, HID };
    av.t[2] = { W1_t2u, as1_t2u, Msrc_t2u, HID, NH, HID };
    av.t[3] = { W1_t2u, ad1_t2u, Mdst_t2u, HID, NH, HID };
    av.t[4] = { W2_u2t, as2_u2t, vsrc2, HC1, 1, OUTC };
    av.t[5] = { W2_u2t, ad2_u2t, vdst2, HC1, 1, OUTC };
    attn_vecs_kernel<<<6, 256, 0, stream>>>(av);

    // ---- zero degree histograms ----
    hipMemsetAsync(deg_t, 0, 150000 * sizeof(int), stream);

    // ---- CSR histogram + prefix scans (no scatter yet) ----
    hist2_kernel<<<(2 * NE + 255) / 256, 256, 0, stream>>>(dst_u2t, dst_u, deg_t, deg_u);
    block_sum2_kernel<<<NB_T + NB_U, 256, 0, stream>>>(deg_t, bsum_t, deg_u, bsum_u);
    scan_bsum2_kernel<<<1, 512, 0, stream>>>(bsum_t, bsum_u);
    scan_final2_kernel<<<NB_T + NB_U, 256, 0, stream>>>(
        deg_t, bsum_t, rowptr_t, cur_t, deg_u, bsum_u, rowptr_u, cur_u);

    // ---- input projections with fused attention-scalar epilogue ----
    gemm_proj_attn<<<dim3(1, (N_TX + 63) / 64), 256, 0, stream>>>(
        x_tx, Wp_tx, bp_tx, h_tx, N_TX, F_TX,
        Mdst_u2t, ald_tx, Msrc_t2u, als_tx);
    gemm_proj_attn<<<dim3(1, (N_USER + 63) / 64), 256, 0, stream>>>(
        x_user, Wp_user, bp_user, h_us, N_USER, F_USER,
        Msrc_u2t, als_us, Mdst_t2u, ald_us);

    // ---- scatter + edge-weight precompute (both edge types) ----
    scatter2_ew_kernel<<<(2 * NE + 255) / 256, 256, 0, stream>>>(
        src_u2t, dst_u2t, cur_t, csr_t, ew_t, als_us, ald_tx,
        src_t2u, dst_u,   cur_u, csr_u, ew_u, als_tx, ald_us);

    // ================= conv1, u2t (dst = tx): agg -> transform -> ald2 partials ==========
    agg_conv1_kernel<<<(N_TX + 3) / 4, 256, 0, stream>>>(
        rowptr_t, csr_t, h_us, ew_t, agg, N_TX);
    transform_v6<<<dim3((N_TX + 63) / 64, NH), 256, 0, stream>>>(
        agg, W1_u2t, b1_u2t, vdst2, ald2p, nullptr, N_TX, 0);

    // ================= conv1, t2u (dst = user): agg -> transform (u1 in place) ==========
    agg_conv1_kernel<<<(N_USER + 3) / 4, 256, 0, stream>>>(
        rowptr_u, csr_u, h_tx, ew_u, agg, N_USER);
    transform_v6<<<dim3((N_USER + 63) / 64, NH), 256, 0, stream>>>(
        agg, W1_t2u, b1_t2u, vsrc2, als2p, agg, N_USER, 1);
    float* u1 = agg;

    // ---- combine head partials ----
    combine_parts<<<(N_TX + N_USER + 255) / 256, 256, 0, stream>>>(
        ald2p, ald2, N_TX, als2p, als2, N_USER);

    // ================= conv2 projection + fused conv2/classifier =================
    gemm_kernel<<<dim3(1, (N_USER + 63) / 64), 256, 0, stream>>>(
        u1, W2_u2t, nullptr, hs2, N_USER, HC1, OUTC, 0);
    conv2_fused_kernel<<<(N_TX + 3) / 4, 256, 0, stream>>>(
        rowptr_t, csr_t, hs2, als2, ald2, b2_u2t, Wc, bc, out, N_TX);
}